// Round 9
// baseline (263.790 us; speedup 1.0000x reference)
//
#include <hip/hip_runtime.h>
#include <stdint.h>

#define NROWS 8192
#define DDIM  256
#define K2    512          // [hi | lo] packed per row
#define MARGIN_F 0.2f

typedef short  short8  __attribute__((ext_vector_type(8)));
typedef float  floatx4 __attribute__((ext_vector_type(4)));

// Static device buffers (avoid depending on ws_size).
__device__ unsigned short gA[(size_t)NROWS * K2];   // im split: [hi | lo]
__device__ unsigned short gB[(size_t)NROWS * K2];   // s  split: [hi | lo]
__device__ float    g_diag[NROWS];
__device__ unsigned g_rowcnt[NROWS];
__device__ unsigned g_rowkey[NROWS];
__device__ unsigned g_colcnt[NROWS];
__device__ unsigned g_colkey[NROWS];

__device__ __forceinline__ unsigned short f2bf_rne(float x){
    unsigned u = __float_as_uint(x);
    return (unsigned short)((u + 0x7FFFu + ((u >> 16) & 1u)) >> 16);
}
__device__ __forceinline__ float bf2f(unsigned short h){
    return __uint_as_float(((unsigned)h) << 16);
}
// monotone float -> uint key (order-preserving), so atomicMax works on floats
__device__ __forceinline__ unsigned fkey(float f){
    unsigned u = __float_as_uint(f);
    return (u & 0x80000000u) ? ~u : (u | 0x80000000u);
}
__device__ __forceinline__ float kinv(unsigned k){
    unsigned u = (k & 0x80000000u) ? (k ^ 0x80000000u) : ~k;
    return __uint_as_float(u);
}

__device__ __forceinline__ void load_lds16(const unsigned short* gptr, void* lptr){
    __builtin_amdgcn_global_load_lds(
        (const __attribute__((address_space(1))) unsigned int*)(uintptr_t)gptr,
        (__attribute__((address_space(3))) unsigned int*)(unsigned)(uintptr_t)lptr,
        16, 0, 0);
}

// One wave per row: fp32 diag dot, hi/lo bf16 split, stats init.
__global__ __launch_bounds__(256) void prep_kernel(const float* __restrict__ im,
                                                   const float* __restrict__ s){
    const int w    = threadIdx.x >> 6;
    const int lane = threadIdx.x & 63;
    const int row  = blockIdx.x * 4 + w;

    const float4 a = ((const float4*)(im + (size_t)row * DDIM))[lane];
    const float4 b = ((const float4*)(s  + (size_t)row * DDIM))[lane];

    float dp = a.x*b.x + a.y*b.y + a.z*b.z + a.w*b.w;
    #pragma unroll
    for (int m = 1; m < 64; m <<= 1) dp += __shfl_xor(dp, m, 64);
    if (lane == 0){
        g_diag[row]   = dp;
        g_rowcnt[row] = 0u; g_rowkey[row] = 0u;
        g_colcnt[row] = 0u; g_colkey[row] = 0u;
    }

    float av[4] = {a.x, a.y, a.z, a.w};
    float bv[4] = {b.x, b.y, b.z, b.w};
    unsigned short ah[4], al[4], bh[4], bl[4];
    #pragma unroll
    for (int i = 0; i < 4; ++i){
        ah[i] = f2bf_rne(av[i]); al[i] = f2bf_rne(av[i] - bf2f(ah[i]));
        bh[i] = f2bf_rne(bv[i]); bl[i] = f2bf_rne(bv[i] - bf2f(bh[i]));
    }
    const size_t base = (size_t)row * K2 + lane * 4;
    *(ushort4*)&gA[base      ] = make_ushort4(ah[0], ah[1], ah[2], ah[3]);
    *(ushort4*)&gA[base + 256] = make_ushort4(al[0], al[1], al[2], al[3]);
    *(ushort4*)&gB[base      ] = make_ushort4(bh[0], bh[1], bh[2], bh[3]);
    *(ushort4*)&gB[base + 256] = make_ushort4(bl[0], bl[1], bl[2], bl[3]);
}

// 128x128 tile, 4 waves of 32x128 (wave-PRIVATE rows), 16x16x32 bf16 MFMA,
// BK=64 chunks over K=256. Min-bytes config (256 KB/block, zero redundancy):
// B (shared) deduped via LDS DMA; A (private) global->reg exactly once,
// software-pipelined one ks ahead.
// R9 inner-loop fix vs R8 (which fell BELOW the VMEM wall, 8.5 vs 11.7 B/cyc):
//   - LDS reads batched per nj-QUAD (8 ds_read_b128 -> one lgkmcnt wait),
//     not interleaved per-nj (ds_read latency ~120cyc was exposed per iter).
//   - pass-major MFMA order: each acc re-touched at distance 8 (~39 cyc),
//     not distance 2 (~9.7 cyc < MFMA latency).
// Regs: 32 B-frag + 32 A-frag + 64 acc ~= 148 unified < 170 cap (256,3).
__global__ __launch_bounds__(256, 3) void gemm_stats_kernel(){
    __shared__ unsigned short T2[128 * 64];   // Bh chunk
    __shared__ unsigned short T3[128 * 64];   // Bl chunk
    __shared__ float drow[128];
    __shared__ float dcol[128];

    const int tid = threadIdx.x;
    const int bid = blockIdx.x;
    // bid[2:0]->band(XCD), bid[5:3]->row within band, bid[11:6]->column
    const int bi  = (bid & 7) * 8 + ((bid >> 3) & 7);
    const int bj  = bid >> 6;

    if (tid < 128) drow[tid]       = g_diag[bi * 128 + tid];
    else           dcol[tid - 128] = g_diag[bj * 128 + (tid - 128)];

    const int w    = tid >> 6, lane = tid & 63;
    const int quad = lane >> 4, l16 = lane & 15;
    const int sw   = l16 & 7;           // read-side swizzle key

    floatx4 acc[2][8] = {};

    const unsigned short* Abase = gA + (size_t)bi * 128 * K2;
    const unsigned short* Bbase = gB + (size_t)bj * 128 * K2;
    // A fragment bases (MFMA A layout: lane(l16,quad) -> row l16, k quad*8+j):
    // wave w owns rows w*32 .. w*32+31 (mi in {0,1} selects 16-row half).
    const unsigned short* AhFrag = Abase + (size_t)(w * 32 + l16) * K2 + quad * 8;
    const unsigned short* AlFrag = AhFrag + 256;

    short8 ah[2][2], al[2][2];     // [buf][mi], double-buffered across ks
    #pragma unroll
    for (int mi = 0; mi < 2; ++mi){
        ah[0][mi] = *(const short8*)(AhFrag + (size_t)(mi * 16) * K2);
        al[0][mi] = *(const short8*)(AlFrag + (size_t)(mi * 16) * K2);
    }
    int cur = 0;

    #pragma unroll 1
    for (int kc = 0; kc < 4; ++kc){
        // ---- stage Bh -> T2, Bl -> T3 (DMA path, dedup through LDS) ----
        #pragma unroll
        for (int q = 0; q < 4; ++q){
            const int o    = q * 4096 + tid * 16;     // LDS byte offset (fixed)
            const int ch   = o >> 4;                  // linear chunk index
            const int r    = ch >> 3;                 // tile row
            const int clog = (ch & 7) ^ (r & 7);      // stored -> logical chunk
            const size_t goff = (size_t)r * K2 + kc * 64 + clog * 8;
            load_lds16(Bbase + goff,       (char*)T2 + o);
            load_lds16(Bbase + goff + 256, (char*)T3 + o);
        }
        __syncthreads();

        #pragma unroll
        for (int ks = 0; ks < 2; ++ks){
            // prefetch A frags for the next ks (or next chunk) — barrier-free
            const int nkc = (ks == 1) ? kc + 1 : kc;
            const int nks = (ks == 1) ? 0 : 1;
            if (!(kc == 3 && ks == 1)){
                #pragma unroll
                for (int mi = 0; mi < 2; ++mi){
                    const size_t off = (size_t)(mi * 16) * K2 + nkc * 64 + nks * 32;
                    ah[cur ^ 1][mi] = *(const short8*)(AhFrag + off);
                    al[cur ^ 1][mi] = *(const short8*)(AlFrag + off);
                }
            }

            const int co = ((ks * 4 + quad) ^ sw) * 8;
            #pragma unroll
            for (int h = 0; h < 2; ++h){
                // batched LDS reads: 8 ds_read_b128, single wait
                short8 bh4[4], bl4[4];
                #pragma unroll
                for (int j = 0; j < 4; ++j){
                    bh4[j] = *(const short8*)&T2[((h * 4 + j) * 16 + l16) * 64 + co];
                    bl4[j] = *(const short8*)&T3[((h * 4 + j) * 16 + l16) * 64 + co];
                }
                // pass 1: Ah*Bh — 8 independent MFMAs
                #pragma unroll
                for (int j = 0; j < 4; ++j){
                    acc[0][h*4+j] = __builtin_amdgcn_mfma_f32_16x16x32_bf16(ah[cur][0], bh4[j], acc[0][h*4+j], 0, 0, 0);
                    acc[1][h*4+j] = __builtin_amdgcn_mfma_f32_16x16x32_bf16(ah[cur][1], bh4[j], acc[1][h*4+j], 0, 0, 0);
                }
                // pass 2: Al*Bh — re-touch distance 8
                #pragma unroll
                for (int j = 0; j < 4; ++j){
                    acc[0][h*4+j] = __builtin_amdgcn_mfma_f32_16x16x32_bf16(al[cur][0], bh4[j], acc[0][h*4+j], 0, 0, 0);
                    acc[1][h*4+j] = __builtin_amdgcn_mfma_f32_16x16x32_bf16(al[cur][1], bh4[j], acc[1][h*4+j], 0, 0, 0);
                }
                // pass 3: Ah*Bl — re-touch distance 8
                #pragma unroll
                for (int j = 0; j < 4; ++j){
                    acc[0][h*4+j] = __builtin_amdgcn_mfma_f32_16x16x32_bf16(ah[cur][0], bl4[j], acc[0][h*4+j], 0, 0, 0);
                    acc[1][h*4+j] = __builtin_amdgcn_mfma_f32_16x16x32_bf16(ah[cur][1], bl4[j], acc[1][h*4+j], 0, 0, 0);
                }
            }
            cur ^= 1;
        }
        __syncthreads();
    }

    // ---- fused stats epilogue ----
    // C/D layout (verified m89/m91): col = lane&15, row = quad*4 + reg.
    // acc[mi][nj]: row = w*32 + mi*16 + quad*4 + r ; col = nj*16 + l16.
    const int rowbase = bi * 128 + w * 32;
    const int colbase = bj * 128;

    // row stats: each lane holds 8 cols (nj); reduce across l16 lanes.
    #pragma unroll
    for (int mi = 0; mi < 2; ++mi){
        #pragma unroll
        for (int r = 0; r < 4; ++r){
            const int lrow = w * 32 + mi * 16 + quad * 4 + r;
            const int gi   = bi * 128 + lrow;
            const float dv = drow[lrow];
            int cnt = 0; float mx = -3.0e38f;
            #pragma unroll
            for (int nj = 0; nj < 8; ++nj){
                const float v  = acc[mi][nj][r];
                const int   gj = colbase + nj * 16 + l16;
                if (gi != gj){                 // exclude diagonal explicitly
                    cnt += (v < dv) ? 1 : 0;
                    mx = fmaxf(mx, v);
                }
            }
            #pragma unroll
            for (int m = 1; m < 16; m <<= 1){
                cnt += __shfl_xor(cnt, m, 64);
                mx   = fmaxf(mx, __shfl_xor(mx, m, 64));
            }
            if (l16 == 0){
                atomicAdd(&g_rowcnt[gi], (unsigned)cnt);
                atomicMax(&g_rowkey[gi], fkey(mx));
            }
        }
    }
    // col stats: each lane holds 8 rows (mi,r) per nj; reduce across quad lanes.
    #pragma unroll
    for (int nj = 0; nj < 8; ++nj){
        const int lcol = nj * 16 + l16;
        const int gj   = bj * 128 + lcol;
        const float dv = dcol[lcol];
        int cnt = 0; float mx = -3.0e38f;
        #pragma unroll
        for (int mi = 0; mi < 2; ++mi){
            #pragma unroll
            for (int r = 0; r < 4; ++r){
                const float v  = acc[mi][nj][r];
                const int   gi = rowbase + mi * 16 + quad * 4 + r;
                if (gi != gj){
                    cnt += (v < dv) ? 1 : 0;
                    mx = fmaxf(mx, v);
                }
            }
        }
        #pragma unroll
        for (int m = 16; m < 64; m <<= 1){
            cnt += __shfl_xor(cnt, m, 64);
            mx   = fmaxf(mx, __shfl_xor(mx, m, 64));
        }
        if (quad == 0){
            atomicAdd(&g_colcnt[gj], (unsigned)cnt);
            atomicMax(&g_colkey[gj], fkey(mx));
        }
    }
}

__global__ __launch_bounds__(256) void finalize_kernel(float* __restrict__ out){
    __shared__ double red[256];
    double acc = 0.0;
    #pragma unroll
    for (int it = 0; it < NROWS / 256; ++it){
        const int i = it * 256 + threadIdx.x;
        const float d  = g_diag[i];
        const float cs  = fmaxf(MARGIN_F + kinv(g_rowkey[i]) - d, 0.0f) * (1.0f / (float)(g_rowcnt[i] + 1u));
        const float cim = fmaxf(MARGIN_F + kinv(g_colkey[i]) - d, 0.0f) * (1.0f / (float)(g_colcnt[i] + 1u));
        acc += (double)cs + (double)cim;
    }
    red[threadIdx.x] = acc;
    __syncthreads();
    for (int s2 = 128; s2 > 0; s2 >>= 1){
        if (threadIdx.x < s2) red[threadIdx.x] += red[threadIdx.x + s2];
        __syncthreads();
    }
    if (threadIdx.x == 0) out[0] = (float)red[0];
}

extern "C" void kernel_launch(void* const* d_in, const int* in_sizes, int n_in,
                              void* d_out, int out_size, void* d_ws, size_t ws_size,
                              hipStream_t stream){
    const float* im = (const float*)d_in[0];
    const float* s  = (const float*)d_in[1];
    float* out = (float*)d_out;

    prep_kernel<<<NROWS / 4, 256, 0, stream>>>(im, s);
    gemm_stats_kernel<<<4096, 256, 0, stream>>>();
    finalize_kernel<<<1, 256, 0, stream>>>(out);
}

// Round 10
// 246.171 us; speedup vs baseline: 1.0716x; 1.0716x over previous
//
#include <hip/hip_runtime.h>
#include <stdint.h>

#define NROWS 8192
#define DDIM  256
#define K2    512          // [hi | lo] packed per row
#define MARGIN_F 0.2f

typedef short  short8  __attribute__((ext_vector_type(8)));
typedef float  floatx4 __attribute__((ext_vector_type(4)));

// Static device buffers (avoid depending on ws_size).
__device__ unsigned short gA[(size_t)NROWS * K2];   // im split: [hi | lo]
__device__ unsigned short gB[(size_t)NROWS * K2];   // s  split: [hi | lo]
__device__ float    g_diag[NROWS];
__device__ unsigned g_rowcnt[NROWS];
__device__ unsigned g_rowkey[NROWS];
__device__ unsigned g_colcnt[NROWS];
__device__ unsigned g_colkey[NROWS];

__device__ __forceinline__ unsigned short f2bf_rne(float x){
    unsigned u = __float_as_uint(x);
    return (unsigned short)((u + 0x7FFFu + ((u >> 16) & 1u)) >> 16);
}
__device__ __forceinline__ float bf2f(unsigned short h){
    return __uint_as_float(((unsigned)h) << 16);
}
// monotone float -> uint key (order-preserving), so atomicMax works on floats
__device__ __forceinline__ unsigned fkey(float f){
    unsigned u = __float_as_uint(f);
    return (u & 0x80000000u) ? ~u : (u | 0x80000000u);
}
__device__ __forceinline__ float kinv(unsigned k){
    unsigned u = (k & 0x80000000u) ? (k ^ 0x80000000u) : ~k;
    return __uint_as_float(u);
}

__device__ __forceinline__ void load_lds16(const unsigned short* gptr, void* lptr){
    __builtin_amdgcn_global_load_lds(
        (const __attribute__((address_space(1))) unsigned int*)(uintptr_t)gptr,
        (__attribute__((address_space(3))) unsigned int*)(unsigned)(uintptr_t)lptr,
        16, 0, 0);
}

// One wave per row: fp32 diag dot, hi/lo bf16 split, stats init.
__global__ __launch_bounds__(256) void prep_kernel(const float* __restrict__ im,
                                                   const float* __restrict__ s){
    const int w    = threadIdx.x >> 6;
    const int lane = threadIdx.x & 63;
    const int row  = blockIdx.x * 4 + w;

    const float4 a = ((const float4*)(im + (size_t)row * DDIM))[lane];
    const float4 b = ((const float4*)(s  + (size_t)row * DDIM))[lane];

    float dp = a.x*b.x + a.y*b.y + a.z*b.z + a.w*b.w;
    #pragma unroll
    for (int m = 1; m < 64; m <<= 1) dp += __shfl_xor(dp, m, 64);
    if (lane == 0){
        g_diag[row]   = dp;
        g_rowcnt[row] = 0u; g_rowkey[row] = 0u;
        g_colcnt[row] = 0u; g_colkey[row] = 0u;
    }

    float av[4] = {a.x, a.y, a.z, a.w};
    float bv[4] = {b.x, b.y, b.z, b.w};
    unsigned short ah[4], al[4], bh[4], bl[4];
    #pragma unroll
    for (int i = 0; i < 4; ++i){
        ah[i] = f2bf_rne(av[i]); al[i] = f2bf_rne(av[i] - bf2f(ah[i]));
        bh[i] = f2bf_rne(bv[i]); bl[i] = f2bf_rne(bv[i] - bf2f(bh[i]));
    }
    const size_t base = (size_t)row * K2 + lane * 4;
    *(ushort4*)&gA[base      ] = make_ushort4(ah[0], ah[1], ah[2], ah[3]);
    *(ushort4*)&gA[base + 256] = make_ushort4(al[0], al[1], al[2], al[3]);
    *(ushort4*)&gB[base      ] = make_ushort4(bh[0], bh[1], bh[2], bh[3]);
    *(ushort4*)&gB[base + 256] = make_ushort4(bl[0], bl[1], bl[2], bl[3]);
}

// 128x128 tile, 4 waves of 32x128 (wave-PRIVATE rows), 16x16x32 bf16 MFMA,
// BK=64 chunks over K=256. Min-bytes (256 KB/block): B (shared) deduped via
// LDS DMA; A (private) global->reg exactly once.
// R10 vs R9: register diet to reach 4 blocks/CU (was 3) — al single-buffered
// (loaded at top of each ks, consumed in pass 2; ah keeps cross-ks prefetch).
// Unified regs ~120 <= 128 cap of __launch_bounds__(256,4); LDS 33KB*4=132<=160.
// Theory: R8/R9 ran at 8.5 B/cyc/CU vs the 11.6 wall of R3/R4/R7 — stall-
// bound, and cross-BLOCK overlap (m114) is the only cover mechanism that has
// worked in this line; +33% resident blocks attacks exactly that.
__global__ __launch_bounds__(256, 4) void gemm_stats_kernel(){
    __shared__ unsigned short T2[128 * 64];   // Bh chunk
    __shared__ unsigned short T3[128 * 64];   // Bl chunk
    __shared__ float drow[128];
    __shared__ float dcol[128];

    const int tid = threadIdx.x;
    const int bid = blockIdx.x;
    // bid[2:0]->band(XCD), bid[5:3]->row within band, bid[11:6]->column
    const int bi  = (bid & 7) * 8 + ((bid >> 3) & 7);
    const int bj  = bid >> 6;

    if (tid < 128) drow[tid]       = g_diag[bi * 128 + tid];
    else           dcol[tid - 128] = g_diag[bj * 128 + (tid - 128)];

    const int w    = tid >> 6, lane = tid & 63;
    const int quad = lane >> 4, l16 = lane & 15;
    const int sw   = l16 & 7;           // read-side swizzle key

    floatx4 acc[2][8] = {};

    const unsigned short* Abase = gA + (size_t)bi * 128 * K2;
    const unsigned short* Bbase = gB + (size_t)bj * 128 * K2;
    // A fragment bases (MFMA A layout: lane(l16,quad) -> row l16, k quad*8+j):
    // wave w owns rows w*32 .. w*32+31 (mi in {0,1} selects 16-row half).
    const unsigned short* AhFrag = Abase + (size_t)(w * 32 + l16) * K2 + quad * 8;
    const unsigned short* AlFrag = AhFrag + 256;

    short8 ah[2][2];               // [buf][mi], double-buffered across ks
    #pragma unroll
    for (int mi = 0; mi < 2; ++mi)
        ah[0][mi] = *(const short8*)(AhFrag + (size_t)(mi * 16) * K2);
    int cur = 0;

    #pragma unroll 1
    for (int kc = 0; kc < 4; ++kc){
        // ---- stage Bh -> T2, Bl -> T3 (DMA path, dedup through LDS) ----
        #pragma unroll
        for (int q = 0; q < 4; ++q){
            const int o    = q * 4096 + tid * 16;     // LDS byte offset (fixed)
            const int ch   = o >> 4;                  // linear chunk index
            const int r    = ch >> 3;                 // tile row
            const int clog = (ch & 7) ^ (r & 7);      // stored -> logical chunk
            const size_t goff = (size_t)r * K2 + kc * 64 + clog * 8;
            load_lds16(Bbase + goff,       (char*)T2 + o);
            load_lds16(Bbase + goff + 256, (char*)T3 + o);
        }
        __syncthreads();

        #pragma unroll
        for (int ks = 0; ks < 2; ++ks){
            // al for THIS ks (single-buffered; consumed in pass 2, ~8 MFMA cover)
            short8 al[2];
            #pragma unroll
            for (int mi = 0; mi < 2; ++mi)
                al[mi] = *(const short8*)(AlFrag + (size_t)(mi * 16) * K2 + kc * 64 + ks * 32);
            // ah prefetch for the next ks / chunk (cross-barrier legal: regs)
            const int nkc = (ks == 1) ? kc + 1 : kc;
            const int nks = (ks == 1) ? 0 : 1;
            if (!(kc == 3 && ks == 1)){
                #pragma unroll
                for (int mi = 0; mi < 2; ++mi)
                    ah[cur ^ 1][mi] = *(const short8*)(AhFrag + (size_t)(mi * 16) * K2 + nkc * 64 + nks * 32);
            }

            const int co = ((ks * 4 + quad) ^ sw) * 8;
            #pragma unroll
            for (int h = 0; h < 2; ++h){
                short8 bh4[4], bl4[4];
                #pragma unroll
                for (int j = 0; j < 4; ++j){
                    bh4[j] = *(const short8*)&T2[((h * 4 + j) * 16 + l16) * 64 + co];
                    bl4[j] = *(const short8*)&T3[((h * 4 + j) * 16 + l16) * 64 + co];
                }
                // pass 1: Ah*Bh
                #pragma unroll
                for (int j = 0; j < 4; ++j){
                    acc[0][h*4+j] = __builtin_amdgcn_mfma_f32_16x16x32_bf16(ah[cur][0], bh4[j], acc[0][h*4+j], 0, 0, 0);
                    acc[1][h*4+j] = __builtin_amdgcn_mfma_f32_16x16x32_bf16(ah[cur][1], bh4[j], acc[1][h*4+j], 0, 0, 0);
                }
                // pass 2: Al*Bh
                #pragma unroll
                for (int j = 0; j < 4; ++j){
                    acc[0][h*4+j] = __builtin_amdgcn_mfma_f32_16x16x32_bf16(al[0], bh4[j], acc[0][h*4+j], 0, 0, 0);
                    acc[1][h*4+j] = __builtin_amdgcn_mfma_f32_16x16x32_bf16(al[1], bh4[j], acc[1][h*4+j], 0, 0, 0);
                }
                // pass 3: Ah*Bl
                #pragma unroll
                for (int j = 0; j < 4; ++j){
                    acc[0][h*4+j] = __builtin_amdgcn_mfma_f32_16x16x32_bf16(ah[cur][0], bl4[j], acc[0][h*4+j], 0, 0, 0);
                    acc[1][h*4+j] = __builtin_amdgcn_mfma_f32_16x16x32_bf16(ah[cur][1], bl4[j], acc[1][h*4+j], 0, 0, 0);
                }
            }
            cur ^= 1;
        }
        __syncthreads();
    }

    // ---- fused stats epilogue ----
    // C/D layout (verified m89/m91): col = lane&15, row = quad*4 + reg.
    // acc[mi][nj]: row = w*32 + mi*16 + quad*4 + r ; col = nj*16 + l16.
    const int rowbase = bi * 128 + w * 32;
    const int colbase = bj * 128;

    // row stats: each lane holds 8 cols (nj); reduce across l16 lanes.
    #pragma unroll
    for (int mi = 0; mi < 2; ++mi){
        #pragma unroll
        for (int r = 0; r < 4; ++r){
            const int lrow = w * 32 + mi * 16 + quad * 4 + r;
            const int gi   = bi * 128 + lrow;
            const float dv = drow[lrow];
            int cnt = 0; float mx = -3.0e38f;
            #pragma unroll
            for (int nj = 0; nj < 8; ++nj){
                const float v  = acc[mi][nj][r];
                const int   gj = colbase + nj * 16 + l16;
                if (gi != gj){                 // exclude diagonal explicitly
                    cnt += (v < dv) ? 1 : 0;
                    mx = fmaxf(mx, v);
                }
            }
            #pragma unroll
            for (int m = 1; m < 16; m <<= 1){
                cnt += __shfl_xor(cnt, m, 64);
                mx   = fmaxf(mx, __shfl_xor(mx, m, 64));
            }
            if (l16 == 0){
                atomicAdd(&g_rowcnt[gi], (unsigned)cnt);
                atomicMax(&g_rowkey[gi], fkey(mx));
            }
        }
    }
    // col stats: each lane holds 8 rows (mi,r) per nj; reduce across quad lanes.
    #pragma unroll
    for (int nj = 0; nj < 8; ++nj){
        const int lcol = nj * 16 + l16;
        const int gj   = bj * 128 + lcol;
        const float dv = dcol[lcol];
        int cnt = 0; float mx = -3.0e38f;
        #pragma unroll
        for (int mi = 0; mi < 2; ++mi){
            #pragma unroll
            for (int r = 0; r < 4; ++r){
                const float v  = acc[mi][nj][r];
                const int   gi = rowbase + mi * 16 + quad * 4 + r;
                if (gi != gj){
                    cnt += (v < dv) ? 1 : 0;
                    mx = fmaxf(mx, v);
                }
            }
        }
        #pragma unroll
        for (int m = 16; m < 64; m <<= 1){
            cnt += __shfl_xor(cnt, m, 64);
            mx   = fmaxf(mx, __shfl_xor(mx, m, 64));
        }
        if (quad == 0){
            atomicAdd(&g_colcnt[gj], (unsigned)cnt);
            atomicMax(&g_colkey[gj], fkey(mx));
        }
    }
}

__global__ __launch_bounds__(256) void finalize_kernel(float* __restrict__ out){
    __shared__ double red[256];
    double acc = 0.0;
    #pragma unroll
    for (int it = 0; it < NROWS / 256; ++it){
        const int i = it * 256 + threadIdx.x;
        const float d  = g_diag[i];
        const float cs  = fmaxf(MARGIN_F + kinv(g_rowkey[i]) - d, 0.0f) * (1.0f / (float)(g_rowcnt[i] + 1u));
        const float cim = fmaxf(MARGIN_F + kinv(g_colkey[i]) - d, 0.0f) * (1.0f / (float)(g_colcnt[i] + 1u));
        acc += (double)cs + (double)cim;
    }
    red[threadIdx.x] = acc;
    __syncthreads();
    for (int s2 = 128; s2 > 0; s2 >>= 1){
        if (threadIdx.x < s2) red[threadIdx.x] += red[threadIdx.x + s2];
        __syncthreads();
    }
    if (threadIdx.x == 0) out[0] = (float)red[0];
}

extern "C" void kernel_launch(void* const* d_in, const int* in_sizes, int n_in,
                              void* d_out, int out_size, void* d_ws, size_t ws_size,
                              hipStream_t stream){
    const float* im = (const float*)d_in[0];
    const float* s  = (const float*)d_in[1];
    float* out = (float*)d_out;

    prep_kernel<<<NROWS / 4, 256, 0, stream>>>(im, s);
    gemm_stats_kernel<<<4096, 256, 0, stream>>>();
    finalize_kernel<<<1, 256, 0, stream>>>(out);
}